// Round 4
// baseline (346.147 us; speedup 1.0000x reference)
//
#include <hip/hip_runtime.h>

#define R_TOTAL 12544
#define NTOK    784
#define CDIM    384
#define INNER   1152
#define NHEAD   8
#define HDIM    48
#define BATCH   16
#define SCALE   0.14433756729740643f   // 48^-0.5

typedef unsigned short u16;
typedef unsigned int   u32;
typedef __attribute__((ext_vector_type(8))) short short8;   // 8 bf16, 4 VGPRs
typedef __attribute__((ext_vector_type(4))) float floatx4;  // MFMA C/D

union V8 { uint4 u; short8 s; u16 h[8]; };

// workspace layout (BYTE offsets) — total 38.56 MB, byte-identical to round-2/3-proven layout.
// Round 1 proved larger layouts corrupt the harness's pristine input copies.
#define OB_OFF     28901376ull   // Yb bf16 [12544,1152] at 0; Ob bf16 [12544,384] here
#define ST_OFF     38535168ull   // fp32 stats: S1[2304] AB1[2304] S2[768] AB2[768]

__device__ __forceinline__ float b2f(u16 u) {
    union { float f; u32 i; } v; v.i = ((u32)u) << 16; return v.f;
}
__device__ __forceinline__ u16 f2b(float f) {
    union { float f; u32 i; } v; v.f = f;
    u32 r = v.i + 0x7FFFu + ((v.i >> 16) & 1u);   // RNE
    return (u16)(r >> 16);
}
__device__ __forceinline__ u32 pk2(float lo, float hi) {
    return (u32)f2b(lo) | ((u32)f2b(hi) << 16);
}
__device__ __forceinline__ float hswish_f(float v) {
    return v * fminf(fmaxf(v + 3.f, 0.f), 6.f) * (1.f / 6.f);
}

__global__ __launch_bounds__(256) void zero_k(float* __restrict__ p, int n) {
    int i = blockIdx.x * 256 + threadIdx.x;
    if (i < n) p[i] = 0.f;
}

// ---------------------------------------------------------------- MFMA GEMM
// A row-major [M,K] (fp32 or bf16, optional hardswish), Bt row-major [N,K] fp32,
// C = A*Bt^T, out bf16 or fp32. 128x128 tile, BK=32, 4 waves of 64x64.
template<int ABF16, int HSW, int OBF16>
__global__ __launch_bounds__(256) void gemm_mfma_k(
    const void* __restrict__ Ap, const float* __restrict__ Bfp,
    void* __restrict__ Cp, int M, int Nout, int K)
{
    __shared__ u16 As[128 * 40];   // row stride 40 shorts (pad 8) -> 2-way banks
    __shared__ u16 Bs[128 * 40];
    const int t = threadIdx.x;
    const int lane = t & 63, wv = t >> 6;
    const int l15 = lane & 15, quad = lane >> 4;
    const int wm = (wv & 1) * 64, wn = (wv >> 1) * 64;
    const int m0 = blockIdx.y * 128, n0 = blockIdx.x * 128;
    const floatx4 zf = {0.f, 0.f, 0.f, 0.f};

    floatx4 acc[4][4];
    #pragma unroll
    for (int i = 0; i < 4; i++)
        #pragma unroll
        for (int j = 0; j < 4; j++) acc[i][j] = zf;

    for (int k0 = 0; k0 < K; k0 += 32) {
        __syncthreads();
        #pragma unroll
        for (int it = 0; it < 2; it++) {
            const int flat = t + it * 256;           // 0..511
            const int rr = flat >> 2, ss = (flat & 3) * 8;
            uint4 aw;
            if (ABF16) {
                uint4 u = *(const uint4*)((const u16*)Ap + (size_t)(m0 + rr) * K + k0 + ss);
                if (HSW) {
                    aw.x = pk2(hswish_f(b2f((u16)(u.x & 0xffff))), hswish_f(b2f((u16)(u.x >> 16))));
                    aw.y = pk2(hswish_f(b2f((u16)(u.y & 0xffff))), hswish_f(b2f((u16)(u.y >> 16))));
                    aw.z = pk2(hswish_f(b2f((u16)(u.z & 0xffff))), hswish_f(b2f((u16)(u.z >> 16))));
                    aw.w = pk2(hswish_f(b2f((u16)(u.w & 0xffff))), hswish_f(b2f((u16)(u.w >> 16))));
                } else {
                    aw = u;
                }
            } else {
                const float* p = (const float*)Ap + (size_t)(m0 + rr) * K + k0 + ss;
                float4 f0 = *(const float4*)p, f1 = *(const float4*)(p + 4);
                aw.x = pk2(f0.x, f0.y); aw.y = pk2(f0.z, f0.w);
                aw.z = pk2(f1.x, f1.y); aw.w = pk2(f1.z, f1.w);
            }
            *(uint4*)&As[rr * 40 + ss] = aw;
            const float* q = Bfp + (size_t)(n0 + rr) * K + k0 + ss;
            float4 g0 = *(const float4*)q, g1 = *(const float4*)(q + 4);
            uint4 bw;
            bw.x = pk2(g0.x, g0.y); bw.y = pk2(g0.z, g0.w);
            bw.z = pk2(g1.x, g1.y); bw.w = pk2(g1.z, g1.w);
            *(uint4*)&Bs[rr * 40 + ss] = bw;
        }
        __syncthreads();
        short8 af[4], bfr[4];
        #pragma unroll
        for (int mi = 0; mi < 4; mi++)
            af[mi] = *(const short8*)&As[(wm + mi * 16 + l15) * 40 + quad * 8];
        #pragma unroll
        for (int ni = 0; ni < 4; ni++)
            bfr[ni] = *(const short8*)&Bs[(wn + ni * 16 + l15) * 40 + quad * 8];
        #pragma unroll
        for (int mi = 0; mi < 4; mi++)
            #pragma unroll
            for (int ni = 0; ni < 4; ni++)
                acc[mi][ni] = __builtin_amdgcn_mfma_f32_16x16x32_bf16(af[mi], bfr[ni], acc[mi][ni], 0, 0, 0);
    }
    #pragma unroll
    for (int mi = 0; mi < 4; mi++) {
        const int mbase = m0 + wm + mi * 16 + quad * 4;
        #pragma unroll
        for (int ni = 0; ni < 4; ni++) {
            const int n = n0 + wn + ni * 16 + l15;
            #pragma unroll
            for (int reg = 0; reg < 4; reg++) {
                size_t off = (size_t)(mbase + reg) * Nout + n;
                float v = acc[mi][ni][reg];
                if (OBF16) ((u16*)Cp)[off] = f2b(v);
                else       ((float*)Cp)[off] = v;
            }
        }
    }
}

// ---------------------------------------------------------------- column stats (sum, sumsq)
template<int BF16>
__global__ __launch_bounds__(128) void col_stats_k(
    const void* __restrict__ Zp, float* __restrict__ sums, int Ncols)
{
    const int col = blockIdx.x * 128 + threadIdx.x;
    const int r0  = blockIdx.y * 256;
    float s = 0.f, s2 = 0.f;
    if (BF16) {
        const u16* Z = (const u16*)Zp;
        for (int r = r0; r < r0 + 256; r++) {
            float v = b2f(Z[(size_t)r * Ncols + col]);
            s += v; s2 += v * v;
        }
    } else {
        const float* Z = (const float*)Zp;
        for (int r = r0; r < r0 + 256; r++) {
            float v = Z[(size_t)r * Ncols + col];
            s += v; s2 += v * v;
        }
    }
    atomicAdd(&sums[col], s);
    atomicAdd(&sums[Ncols + col], s2);
}

__global__ __launch_bounds__(256) void finalize_bn_k(
    const float* __restrict__ sums, const float* __restrict__ g,
    const float* __restrict__ bvec, float* __restrict__ ab, int Ncols, float invM)
{
    int c = blockIdx.x * 256 + threadIdx.x;
    if (c >= Ncols) return;
    float mean = sums[c] * invM;
    float var  = sums[Ncols + c] * invM - mean * mean;
    float a    = g[c] * rsqrtf(var + 1e-5f);
    ab[c] = a;
    ab[Ncols + c] = bvec[c] - mean * a;
}

// fp32 in-place BN apply (for final output)
__global__ __launch_bounds__(256) void bn_apply_k(
    float* __restrict__ Z, const float* __restrict__ ab, int Ncols, int total4)
{
    for (int i4 = blockIdx.x * 256 + threadIdx.x; i4 < total4; i4 += gridDim.x * 256) {
        int col = (i4 * 4) % Ncols;
        float4 z  = *(float4*)(Z + (size_t)i4 * 4);
        float4 a4 = *(const float4*)(ab + col);
        float4 b4 = *(const float4*)(ab + Ncols + col);
        z.x = a4.x * z.x + b4.x; z.y = a4.y * z.y + b4.y;
        z.z = a4.z * z.z + b4.z; z.w = a4.w * z.w + b4.w;
        *(float4*)(Z + (size_t)i4 * 4) = z;
    }
}

// bf16 in-place BN apply (pre-applies BN1 to Yb so attention stages plain copies)
__global__ __launch_bounds__(256) void bn_apply_bf16_k(
    u16* __restrict__ Z, const float* __restrict__ ab, int Ncols, int total8)
{
    int i8 = blockIdx.x * 256 + threadIdx.x;
    if (i8 >= total8) return;
    int col = (i8 * 8) % Ncols;
    uint4 u = *(uint4*)(Z + (size_t)i8 * 8);
    float4 A0 = *(const float4*)(ab + col),        A1 = *(const float4*)(ab + col + 4);
    float4 B0 = *(const float4*)(ab + Ncols + col), B1 = *(const float4*)(ab + Ncols + col + 4);
    uint4 o;
    o.x = pk2(fmaf(b2f((u16)(u.x & 0xffff)), A0.x, B0.x), fmaf(b2f((u16)(u.x >> 16)), A0.y, B0.y));
    o.y = pk2(fmaf(b2f((u16)(u.y & 0xffff)), A0.z, B0.z), fmaf(b2f((u16)(u.y >> 16)), A0.w, B0.w));
    o.z = pk2(fmaf(b2f((u16)(u.z & 0xffff)), A1.x, B1.x), fmaf(b2f((u16)(u.z >> 16)), A1.y, B1.y));
    o.w = pk2(fmaf(b2f((u16)(u.w & 0xffff)), A1.z, B1.z), fmaf(b2f((u16)(u.w >> 16)), A1.w, B1.w));
    *(uint4*)(Z + (size_t)i8 * 8) = o;
}

// ---------------------------------------------------------------- MFMA flash attention
// grid (bh=128, qt=13): all q-tiles of one (b,h) land on the same XCD (bh%8) -> K/V L2-resident.
// BN pre-applied to Y. Register prefetch of next K/V tile overlaps global latency with compute.
__global__ __launch_bounds__(256) void attn_mfma_k(
    const u16* __restrict__ Y,
    const float* __restrict__ biases, const int* __restrict__ idxs,
    u16* __restrict__ O)
{
    __shared__ u16 kt[64 * 72];        // [key][hd padded to 64, stride 72]
    __shared__ u16 vt[48 * 72];        // [hd][key, stride 72] (transposed)
    __shared__ u16 psm[4][16 * 72];    // per-wave P [q][key, stride 72]
    __shared__ float hb[NTOK];

    const int t = threadIdx.x;
    const int lane = t & 63, wv = t >> 6;
    const int l15 = lane & 15, quad = lane >> 4;
    const int bh = blockIdx.x;
    const int b = bh >> 3, h = bh & 7;
    const int qt = blockIdx.y;
    const int n0 = qt * 64;
    const int bN = b * NTOK;
    const int colQ = h * HDIM, colK = CDIM + colQ, colV = 2 * CDIM + colQ;
    const floatx4 zf = {0.f, 0.f, 0.f, 0.f};

    if (t < 196) *(float4*)&hb[t << 2] = *(const float4*)(biases + (size_t)h * NTOK + (t << 2));
    if (t < 128) {   // zero the hd 48..63 pad of kt (QK chunk1 reads zeros there)
        uint4 z = make_uint4(0u, 0u, 0u, 0u);
        *(uint4*)&kt[(t >> 1) * 72 + 48 + (t & 1) * 8] = z;
    }

    // Q fragments (A-layout: m=l15, k=quad*8+j); chunk1 zero-padded past hd=48
    short8 qf0, qf1;
    {
        V8 a0, a1;
        a0.u = make_uint4(0u, 0u, 0u, 0u); a1.u = a0.u;
        int q = n0 + wv * 16 + l15;
        if (q < NTOK) {
            const u16* src = Y + (size_t)(bN + q) * INNER + colQ;
            a0.u = *(const uint4*)(src + quad * 8);
            if (quad < 2) a1.u = *(const uint4*)(src + 32 + quad * 8);
        }
        qf0 = a0.s; qf1 = a1.s;
    }

    // staging work items: 64 keys x 6 segs of 8 hd = 384; thread t owns item t and (t<128) item 256+t
    const int r0s = t >> 2;                 // wrong granularity? no: item f -> r=f/6, s=(f%6)*8
    (void)r0s;
    const int f0 = t,      r0 = f0 / 6, s80 = (f0 % 6) * 8;
    const int f1 = 256 + t, r1 = f1 / 6, s81 = (f1 % 6) * 8;
    const bool own1 = (t < 128);

    V8 pk0, pv0, pk1, pv1;

    // prefetch tile 0
    {
        const int key0 = r0;
        pk0.u = *(const uint4*)(Y + (size_t)(bN + key0) * INNER + colK + s80);
        pv0.u = *(const uint4*)(Y + (size_t)(bN + key0) * INNER + colV + s80);
        if (own1) {
            const int key1 = r1;
            pk1.u = *(const uint4*)(Y + (size_t)(bN + key1) * INNER + colK + s81);
            pv1.u = *(const uint4*)(Y + (size_t)(bN + key1) * INNER + colV + s81);
        }
    }

    float mrun[4], lrun[4];
    floatx4 oacc[3];
    #pragma unroll
    for (int i = 0; i < 4; i++) { mrun[i] = -1e30f; lrun[i] = 0.f; }
    #pragma unroll
    for (int i = 0; i < 3; i++) oacc[i] = zf;

    for (int mt = 0; mt < 13; mt++) {
        const int m0k = mt * 64;
        __syncthreads();   // prev iter done consuming kt/vt; also fences hb/pad/psm
        // ---- store staged tile
        *(uint4*)&kt[r0 * 72 + s80] = pk0.u;
        #pragma unroll
        for (int j = 0; j < 8; j++) vt[(s80 + j) * 72 + r0] = pv0.h[j];
        if (own1) {
            *(uint4*)&kt[r1 * 72 + s81] = pk1.u;
            #pragma unroll
            for (int j = 0; j < 8; j++) vt[(s81 + j) * 72 + r1] = pv1.h[j];
        }
        __syncthreads();

        // ---- prefetch next tile (overlaps with QK/softmax/PV below)
        if (mt + 1 < 13) {
            const int mn = (mt + 1) * 64;
            const int key0 = mn + r0;
            uint4 z = make_uint4(0u, 0u, 0u, 0u);
            pk0.u = z; pv0.u = z;
            if (key0 < NTOK) {
                pk0.u = *(const uint4*)(Y + (size_t)(bN + key0) * INNER + colK + s80);
                pv0.u = *(const uint4*)(Y + (size_t)(bN + key0) * INNER + colV + s80);
            }
            if (own1) {
                const int key1 = mn + r1;
                pk1.u = z; pv1.u = z;
                if (key1 < NTOK) {
                    pk1.u = *(const uint4*)(Y + (size_t)(bN + key1) * INNER + colK + s81);
                    pv1.u = *(const uint4*)(Y + (size_t)(bN + key1) * INNER + colV + s81);
                }
            }
        }

        // ---- QK^T: D[q=quad*4+reg][key=sub*16+l15]
        floatx4 sf[4];
        #pragma unroll
        for (int sub = 0; sub < 4; sub++) {
            const u16* kr = &kt[(sub * 16 + l15) * 72 + quad * 8];
            short8 kb0 = *(const short8*)kr;
            short8 kb1 = *(const short8*)(kr + 32);
            floatx4 c = zf;
            c = __builtin_amdgcn_mfma_f32_16x16x32_bf16(qf0, kb0, c, 0, 0, 0);
            c = __builtin_amdgcn_mfma_f32_16x16x32_bf16(qf1, kb1, c, 0, 0, 0);
            sf[sub] = c;
        }

        // ---- scale + gathered bias + mask + online softmax + P->LDS (bf16)
        #pragma unroll
        for (int reg = 0; reg < 4; reg++) {
            int q = n0 + wv * 16 + quad * 4 + reg;
            int qc = q < NTOK ? q : NTOK - 1;
            const int* idxrow = idxs + (size_t)qc * NTOK;
            float sv[4];
            #pragma unroll
            for (int sub = 0; sub < 4; sub++) {
                int key = m0k + sub * 16 + l15;
                int keyc = key < NTOK ? key : NTOK - 1;
                float x = fmaf(sf[sub][reg], SCALE, hb[idxrow[keyc]]);
                sv[sub] = (key < NTOK) ? x : -1e30f;
            }
            float mx = fmaxf(fmaxf(sv[0], sv[1]), fmaxf(sv[2], sv[3]));
            mx = fmaxf(mx, __shfl_xor(mx, 1));
            mx = fmaxf(mx, __shfl_xor(mx, 2));
            mx = fmaxf(mx, __shfl_xor(mx, 4));
            mx = fmaxf(mx, __shfl_xor(mx, 8));
            float mnew = fmaxf(mrun[reg], mx);
            float al = __expf(mrun[reg] - mnew);
            float psum = 0.f;
            u16* prow = &psm[wv][(quad * 4 + reg) * 72 + l15];
            #pragma unroll
            for (int sub = 0; sub < 4; sub++) {
                float p = __expf(sv[sub] - mnew);
                psum += p;
                prow[sub * 16] = f2b(p);
            }
            psum += __shfl_xor(psum, 1);
            psum += __shfl_xor(psum, 2);
            psum += __shfl_xor(psum, 4);
            psum += __shfl_xor(psum, 8);
            lrun[reg] = lrun[reg] * al + psum;
            mrun[reg] = mnew;
            oacc[0][reg] *= al; oacc[1][reg] *= al; oacc[2][reg] *= al;
        }

        // ---- PV: A=P (own wave's LDS tile), B=V^T
        #pragma unroll
        for (int kc = 0; kc < 2; kc++) {
            short8 pa = *(const short8*)&psm[wv][l15 * 72 + kc * 32 + quad * 8];
            #pragma unroll
            for (int ns = 0; ns < 3; ns++) {
                short8 vb = *(const short8*)&vt[(ns * 16 + l15) * 72 + kc * 32 + quad * 8];
                oacc[ns] = __builtin_amdgcn_mfma_f32_16x16x32_bf16(pa, vb, oacc[ns], 0, 0, 0);
            }
        }
    }

    // ---- epilogue: O[q][h*48 + ns*16 + l15] = hardswish(oacc/l)  (hswish fused; gemm2 HSW=0)
    #pragma unroll
    for (int reg = 0; reg < 4; reg++) {
        int q = n0 + wv * 16 + quad * 4 + reg;
        if (q < NTOK) {
            float rl = 1.f / lrun[reg];
            u16* dst = O + (size_t)(bN + q) * CDIM + colQ;
            dst[l15]      = f2b(hswish_f(oacc[0][reg] * rl));
            dst[16 + l15] = f2b(hswish_f(oacc[1][reg] * rl));
            dst[32 + l15] = f2b(hswish_f(oacc[2][reg] * rl));
        }
    }
}

// ---------------------------------------------------------------- launch
extern "C" void kernel_launch(void* const* d_in, const int* in_sizes, int n_in,
                              void* d_out, int out_size, void* d_ws, size_t ws_size,
                              hipStream_t stream)
{
    const float* x     = (const float*)d_in[0];
    const float* Wqkv  = (const float*)d_in[1];
    const float* g1    = (const float*)d_in[2];
    const float* b1    = (const float*)d_in[3];
    const float* Wproj = (const float*)d_in[4];
    const float* g2    = (const float*)d_in[5];
    const float* b2    = (const float*)d_in[6];
    const float* bias  = (const float*)d_in[7];
    const int*   idxs  = (const int*)d_in[8];
    float* out = (float*)d_out;
    char*  wsb = (char*)d_ws;

    u16*   Yb  = (u16*)wsb;                    // 28.9 MB
    u16*   Ob  = (u16*)(wsb + OB_OFF);         // 9.6 MB
    float* S1  = (float*)(wsb + ST_OFF);       // 2304
    float* AB1 = S1 + 2304;                    // 2304
    float* S2  = AB1 + 2304;                   // 768
    float* AB2 = S2 + 768;                     // 768

    zero_k<<<24, 256, 0, stream>>>(S1, 6144);

    // GEMM1 (MFMA): Ybf16 = x @ Wqkv^T   [12544,1152]
    gemm_mfma_k<0, 0, 1><<<dim3(INNER / 128, R_TOTAL / 128), 256, 0, stream>>>(
        x, Wqkv, Yb, R_TOTAL, INNER, CDIM);

    // BN1 stats -> a, bb; then pre-apply BN to Yb in place
    col_stats_k<1><<<dim3(INNER / 128, R_TOTAL / 256), 128, 0, stream>>>(Yb, S1, INNER);
    finalize_bn_k<<<(INNER + 255) / 256, 256, 0, stream>>>(S1, g1, b1, AB1, INNER, 1.f / R_TOTAL);
    bn_apply_bf16_k<<<(R_TOTAL * INNER / 8 + 255) / 256, 256, 0, stream>>>(
        Yb, AB1, INNER, R_TOTAL * INNER / 8);

    // attention (MFMA, XCD-swizzled grid, reg-prefetch pipeline, hardswish fused in epilogue)
    attn_mfma_k<<<dim3(NHEAD * BATCH, 13), 256, 0, stream>>>(Yb, bias, idxs, Ob);

    // GEMM2 (MFMA): out = O_hsw @ Wproj^T   [12544,384]
    gemm_mfma_k<1, 0, 0><<<dim3(CDIM / 128, R_TOTAL / 128), 256, 0, stream>>>(
        Ob, Wproj, out, R_TOTAL, CDIM, CDIM);

    // BN2 stats -> normalize out in place
    col_stats_k<0><<<dim3(CDIM / 128, R_TOTAL / 256), 128, 0, stream>>>(out, S2, CDIM);
    finalize_bn_k<<<(CDIM + 255) / 256, 256, 0, stream>>>(S2, g2, b2, AB2, CDIM, 1.f / R_TOTAL);
    bn_apply_k<<<1024, 256, 0, stream>>>(out, AB2, CDIM, (R_TOTAL * CDIM) / 4);
}